// Round 1
// baseline (752.589 us; speedup 1.0000x reference)
//
#include <hip/hip_runtime.h>

#define NN 50000
#define NE 800000
#define DD 128

__global__ void deg_kernel(const int* __restrict__ src, const int* __restrict__ dst,
                           int* __restrict__ out_deg, int* __restrict__ in_deg, int E) {
    int i = blockIdx.x * blockDim.x + threadIdx.x;
    if (i < E) {
        atomicAdd(&out_deg[src[i]], 1);
        atomicAdd(&in_deg[dst[i]], 1);
    }
}

// One wave (64 lanes) per edge. Lane l handles elements 2l, 2l+1 of the D=128 row.
__global__ void scatter_kernel(const int* __restrict__ feat, const int* __restrict__ src,
                               const int* __restrict__ dst, const float* __restrict__ emb,
                               const int* __restrict__ out_deg, float* __restrict__ out, int E) {
    int edge = blockIdx.x * (blockDim.x >> 6) + (threadIdx.x >> 6);
    int lane = threadIdx.x & 63;
    if (edge >= E) return;
    int s = src[edge];
    int t = dst[edge];
    float norm = rsqrtf((float)max(out_deg[s], 1));
    int f = feat[s];
    const float2* erow = (const float2*)(emb + (size_t)f * DD);
    float2 v = erow[lane];
    float* orow = out + (size_t)t * DD;
    atomicAdd(&orow[lane * 2], v.x * norm);
    atomicAdd(&orow[lane * 2 + 1], v.y * norm);
}

__global__ void finalize_kernel(float* __restrict__ out, const int* __restrict__ in_deg,
                                const float* __restrict__ bias) {
    int idx = blockIdx.x * blockDim.x + threadIdx.x;
    if (idx >= NN * DD) return;
    int n = idx >> 7;
    int d = idx & 127;
    float norm = rsqrtf((float)max(in_deg[n], 1));
    out[idx] = out[idx] * norm + bias[d];
}

extern "C" void kernel_launch(void* const* d_in, const int* in_sizes, int n_in,
                              void* d_out, int out_size, void* d_ws, size_t ws_size,
                              hipStream_t stream) {
    const int* feat = (const int*)d_in[0];
    const int* src  = (const int*)d_in[1];
    const int* dst  = (const int*)d_in[2];
    const float* emb  = (const float*)d_in[3];
    const float* bias = (const float*)d_in[4];
    float* out = (float*)d_out;

    int* out_deg = (int*)d_ws;
    int* in_deg  = out_deg + NN;

    // Zero accumulators every call (harness does not re-poison between replays).
    hipMemsetAsync(out, 0, (size_t)NN * DD * sizeof(float), stream);
    hipMemsetAsync(out_deg, 0, 2 * NN * sizeof(int), stream);

    {
        int threads = 256;
        int blocks = (NE + threads - 1) / threads;
        deg_kernel<<<blocks, threads, 0, stream>>>(src, dst, out_deg, in_deg, NE);
    }
    {
        int threads = 256;                       // 4 edges per block
        int blocks = (NE + 3) / 4;
        scatter_kernel<<<blocks, threads, 0, stream>>>(feat, src, dst, emb, out_deg, out, NE);
    }
    {
        int threads = 256;
        int blocks = (NN * DD + threads - 1) / threads;
        finalize_kernel<<<blocks, threads, 0, stream>>>(out, in_deg, bias);
    }
}

// Round 2
// 197.846 us; speedup vs baseline: 3.8039x; 3.8039x over previous
//
#include <hip/hip_runtime.h>

#define NN 50000
#define NE 800000
#define DD 128
#define NB ((NN + 255) / 256)   // 196 blocks for scan

__global__ void deg_kernel(const int* __restrict__ src, const int* __restrict__ dst,
                           int* __restrict__ out_deg, int* __restrict__ in_deg) {
    int i = blockIdx.x * blockDim.x + threadIdx.x;
    if (i < NE) {
        atomicAdd(&out_deg[src[i]], 1);
        atomicAdd(&in_deg[dst[i]], 1);
    }
}

// Per-block partial sums of in_deg
__global__ void partial_kernel(const int* __restrict__ in_deg, int* __restrict__ part) {
    __shared__ int tmp[256];
    int t = threadIdx.x;
    int i = blockIdx.x * 256 + t;
    tmp[t] = (i < NN) ? in_deg[i] : 0;
    __syncthreads();
    for (int off = 128; off > 0; off >>= 1) {
        if (t < off) tmp[t] += tmp[t + off];
        __syncthreads();
    }
    if (t == 0) part[blockIdx.x] = tmp[0];
}

// Single block: exclusive scan of the NB partials (NB=196 <= 256)
__global__ void scanpart_kernel(int* __restrict__ part) {
    __shared__ int tmp[256];
    int t = threadIdx.x;
    int v = (t < NB) ? part[t] : 0;
    tmp[t] = v;
    __syncthreads();
    for (int off = 1; off < 256; off <<= 1) {
        int x = (t >= off) ? tmp[t - off] : 0;
        __syncthreads();
        tmp[t] += x;
        __syncthreads();
    }
    if (t < NB) part[t] = tmp[t] - v;   // exclusive block base
}

// Per-element exclusive scan -> node_base
__global__ void base_kernel(const int* __restrict__ in_deg, const int* __restrict__ part,
                            int* __restrict__ node_base) {
    __shared__ int tmp[256];
    int t = threadIdx.x;
    int i = blockIdx.x * 256 + t;
    int v = (i < NN) ? in_deg[i] : 0;
    tmp[t] = v;
    __syncthreads();
    for (int off = 1; off < 256; off <<= 1) {
        int x = (t >= off) ? tmp[t - off] : 0;
        __syncthreads();
        tmp[t] += x;
        __syncthreads();
    }
    if (i < NN) node_base[i] = part[blockIdx.x] + tmp[t] - v;   // exclusive
}

// Counting-sort edges by dst: sorted_src[slot] = src[e]
__global__ void sort_kernel(const int* __restrict__ src, const int* __restrict__ dst,
                            const int* __restrict__ node_base, int* __restrict__ cursor,
                            int* __restrict__ sorted_src) {
    int e = blockIdx.x * blockDim.x + threadIdx.x;
    if (e < NE) {
        int d = dst[e];
        int pos = node_base[d] + atomicAdd(&cursor[d], 1);
        sorted_src[pos] = src[e];
    }
}

// One wave per dst node: register accumulation, fused norm_r + bias, single write.
__global__ void gather_kernel(const int* __restrict__ feat, const int* __restrict__ emb_dummy,
                              const float* __restrict__ emb, const int* __restrict__ out_deg,
                              const int* __restrict__ in_deg, const int* __restrict__ node_base,
                              const int* __restrict__ sorted_src, const float* __restrict__ bias,
                              float* __restrict__ out) {
    int wid = (blockIdx.x * blockDim.x + threadIdx.x) >> 6;
    int lane = threadIdx.x & 63;
    if (wid >= NN) return;
    int beg = node_base[wid];
    int cnt = in_deg[wid];
    float2 acc = make_float2(0.f, 0.f);
    int j = 0;
    for (; j + 1 < cnt; j += 2) {
        int s0 = sorted_src[beg + j];
        int s1 = sorted_src[beg + j + 1];
        int f0 = feat[s0];
        int f1 = feat[s1];
        float nl0 = rsqrtf((float)max(out_deg[s0], 1));
        float nl1 = rsqrtf((float)max(out_deg[s1], 1));
        float2 v0 = ((const float2*)(emb + (size_t)f0 * DD))[lane];
        float2 v1 = ((const float2*)(emb + (size_t)f1 * DD))[lane];
        acc.x += v0.x * nl0 + v1.x * nl1;
        acc.y += v0.y * nl0 + v1.y * nl1;
    }
    if (j < cnt) {
        int s0 = sorted_src[beg + j];
        int f0 = feat[s0];
        float nl0 = rsqrtf((float)max(out_deg[s0], 1));
        float2 v0 = ((const float2*)(emb + (size_t)f0 * DD))[lane];
        acc.x += v0.x * nl0;
        acc.y += v0.y * nl0;
    }
    float nr = rsqrtf((float)max(cnt, 1));
    float2 b = ((const float2*)bias)[lane];
    float2 r = make_float2(acc.x * nr + b.x, acc.y * nr + b.y);
    ((float2*)(out + (size_t)wid * DD))[lane] = r;
}

extern "C" void kernel_launch(void* const* d_in, const int* in_sizes, int n_in,
                              void* d_out, int out_size, void* d_ws, size_t ws_size,
                              hipStream_t stream) {
    const int* feat = (const int*)d_in[0];
    const int* src  = (const int*)d_in[1];
    const int* dst  = (const int*)d_in[2];
    const float* emb  = (const float*)d_in[3];
    const float* bias = (const float*)d_in[4];
    float* out = (float*)d_out;

    int* out_deg   = (int*)d_ws;           // NN
    int* in_deg    = out_deg + NN;         // NN
    int* cursor    = in_deg + NN;          // NN
    int* node_base = cursor + NN;          // NN
    int* part      = node_base + NN;       // 256
    int* sorted    = part + 256;           // NE

    // Zero only the atomic accumulators (everything else is fully overwritten).
    hipMemsetAsync(out_deg, 0, 3 * NN * sizeof(int), stream);

    deg_kernel<<<(NE + 255) / 256, 256, 0, stream>>>(src, dst, out_deg, in_deg);
    partial_kernel<<<NB, 256, 0, stream>>>(in_deg, part);
    scanpart_kernel<<<1, 256, 0, stream>>>(part);
    base_kernel<<<NB, 256, 0, stream>>>(in_deg, part, node_base);
    sort_kernel<<<(NE + 255) / 256, 256, 0, stream>>>(src, dst, node_base, cursor, sorted);
    gather_kernel<<<(NN * 64 + 255) / 256, 256, 0, stream>>>(feat, nullptr, emb, out_deg,
                                                             in_deg, node_base, sorted, bias, out);
}